// Round 1
// baseline (16353.510 us; speedup 1.0000x reference)
//
#include <hip/hip_runtime.h>
#include <math.h>

#define BATCH 8

__device__ __forceinline__ int refl(int p, int n){ return p<0 ? -p : (p>=n ? 2*n-2-p : p); }

// ---------------- 7x7 conv with reflect pad 3 (stride 1), optional tanh ----------------
template<int CIN, bool TANH>
__global__ void conv7_reflect(const float* __restrict__ in, const float* __restrict__ w,
                              const float* __restrict__ bias, float* __restrict__ out,
                              int Cout, int H, int W, int total){
  int idx = blockIdx.x*blockDim.x + threadIdx.x;
  if (idx >= total) return;
  int x = idx % W; int t = idx / W;
  int y = t % H;   t /= H;
  int co = t % Cout; int b = t / Cout;
  int ry[7], rx[7];
  #pragma unroll
  for (int k=0;k<7;k++){ ry[k]=refl(y+k-3,H); rx[k]=refl(x+k-3,W); }
  float acc = bias[co];
  const float* wp = w + co*CIN*49;
  const float* ip = in + (b*CIN)*(H*W);
  for (int ci=0; ci<CIN; ++ci){
    const float* ipc = ip + ci*(H*W);
    const float* wc  = wp + ci*49;
    #pragma unroll
    for (int ky=0; ky<7; ++ky){
      const float* row = ipc + ry[ky]*W;
      #pragma unroll
      for (int kx=0; kx<7; ++kx) acc = fmaf(row[rx[kx]], wc[ky*7+kx], acc);
    }
  }
  if (TANH) acc = tanhf(acc);
  out[idx] = acc;
}

// ---------------- 3x3 stride-2 conv, zero pad 1 ----------------
template<int CIN>
__global__ void conv3s2(const float* __restrict__ in, const float* __restrict__ w,
                        const float* __restrict__ bias, float* __restrict__ out,
                        int Cout, int Hin, int Win, int total){
  int idx = blockIdx.x*blockDim.x + threadIdx.x;
  if (idx >= total) return;
  int Hout = Hin>>1, Wout = Win>>1;
  int x = idx % Wout; int t = idx / Wout;
  int y = t % Hout;   t /= Hout;
  int co = t % Cout;  int b = t / Cout;
  float acc = bias[co];
  const float* wco = w + co*CIN*9;
  const float* inb = in + (b*CIN)*(Hin*Win);
  int iy0 = 2*y-1, ix0 = 2*x-1;
  for (int ci=0; ci<CIN; ++ci){
    const float* ip = inb + ci*(Hin*Win);
    const float* wp = wco + ci*9;
    #pragma unroll
    for (int ky=0; ky<3; ++ky){
      int iy = iy0+ky;
      if ((unsigned)iy < (unsigned)Hin){
        const float* row = ip + iy*Win;
        #pragma unroll
        for (int kx=0; kx<3; ++kx){
          int ix = ix0+kx;
          if ((unsigned)ix < (unsigned)Win)
            acc = fmaf(row[ix], wp[ky*3+kx], acc);
        }
      }
    }
  }
  out[idx] = acc;
}

// ---------------- transposed conv k=3 s=2 p=1 op=1; w layout (Cin, Cout, 3, 3) ----------------
template<int CIN>
__global__ void tconv3(const float* __restrict__ in, const float* __restrict__ w,
                       const float* __restrict__ bias, float* __restrict__ out,
                       int Cout, int Hin, int Win, int total){
  int idx = blockIdx.x*blockDim.x + threadIdx.x;
  if (idx >= total) return;
  int Hout = Hin*2, Wout = Win*2;
  int x = idx % Wout; int t = idx / Wout;
  int y = t % Hout;   t /= Hout;
  int co = t % Cout;  int b = t / Cout;
  int iy[2], wky[2], ny=0;
  int ix[2], wkx[2], nx=0;
  #pragma unroll
  for (int k=0;k<3;k++){
    int d = y+k-1;
    if (d>=0 && (d&1)==0 && (d>>1)<Hin){ iy[ny]=d>>1; wky[ny]=2-k; ny++; }
    d = x+k-1;
    if (d>=0 && (d&1)==0 && (d>>1)<Win){ ix[nx]=d>>1; wkx[nx]=2-k; nx++; }
  }
  float acc = bias[co];
  const float* ib = in + (b*CIN)*(Hin*Win);
  for (int ci=0; ci<CIN; ++ci){
    const float* ic = ib + ci*(Hin*Win);
    const float* wc = w + (ci*Cout + co)*9;
    for (int a=0;a<ny;a++){
      const float* row = ic + iy[a]*Win;
      const float* wr  = wc + wky[a]*3;
      for (int e=0;e<nx;e++)
        acc = fmaf(row[ix[e]], wr[wkx[e]], acc);
    }
  }
  out[idx] = acc;
}

// ---------------- instance-norm stats: one block per (b,c) ----------------
__global__ void in_stats(const float* __restrict__ x, float* __restrict__ mean,
                         float* __restrict__ invstd, int HW){
  int bc = blockIdx.x;
  const float* p = x + (long)bc*HW;
  float s=0.f, s2=0.f;
  for (int i=threadIdx.x; i<HW; i+=blockDim.x){ float v=p[i]; s+=v; s2=fmaf(v,v,s2); }
  #pragma unroll
  for (int o=32;o>0;o>>=1){ s += __shfl_down(s,o); s2 += __shfl_down(s2,o); }
  __shared__ float sh[8];
  int lane = threadIdx.x & 63, wid = threadIdx.x >> 6;
  if (lane==0){ sh[wid]=s; sh[4+wid]=s2; }
  __syncthreads();
  if (threadIdx.x==0){
    float S  = sh[0]+sh[1]+sh[2]+sh[3];
    float S2 = sh[4]+sh[5]+sh[6]+sh[7];
    float m = S/HW;
    float v = S2/HW - m*m; v = fmaxf(v, 0.f);
    mean[bc]   = m;
    invstd[bc] = rsqrtf(v + 1e-5f);
  }
}

// ---------------- normalize + ReLU in place (float4) ----------------
__global__ void norm_relu4(float4* __restrict__ x, const float* __restrict__ mean,
                           const float* __restrict__ invstd, int log2HW, int total4){
  int idx = blockIdx.x*blockDim.x + threadIdx.x;
  if (idx >= total4) return;
  int bc = (idx<<2) >> log2HW;
  float m = mean[bc], is = invstd[bc];
  float4 v = x[idx];
  v.x = fmaxf((v.x-m)*is, 0.f);
  v.y = fmaxf((v.y-m)*is, 0.f);
  v.z = fmaxf((v.z-m)*is, 0.f);
  v.w = fmaxf((v.w-m)*is, 0.f);
  x[idx] = v;
}

// ---------------- per-(b,id) scatter-mean: accumulate ----------------
__global__ void pool_accum(const float* __restrict__ t, const int* __restrict__ imap,
                           float* __restrict__ sums, float* __restrict__ cnts){
  const int P = 512*512;
  int b = blockIdx.y;
  __shared__ float ls[96];
  __shared__ float lc[32];
  for (int i=threadIdx.x;i<96;i+=blockDim.x) ls[i]=0.f;
  if (threadIdx.x<32) lc[threadIdx.x]=0.f;
  __syncthreads();
  const float* tb = t + b*3*P;
  const int*   mb = imap + b*P;
  for (int p = blockIdx.x*blockDim.x + threadIdx.x; p < P; p += gridDim.x*blockDim.x){
    int id = mb[p];
    atomicAdd(&ls[id*3+0], tb[p]);
    atomicAdd(&ls[id*3+1], tb[P+p]);
    atomicAdd(&ls[id*3+2], tb[2*P+p]);
    atomicAdd(&lc[id], 1.0f);
  }
  __syncthreads();
  for (int i=threadIdx.x;i<96;i+=blockDim.x) atomicAdd(&sums[b*96+i], ls[i]);
  if (threadIdx.x<32) atomicAdd(&cnts[b*32+threadIdx.x], lc[threadIdx.x]);
}

// ---------------- broadcast means back ----------------
__global__ void pool_bcast(float* __restrict__ out, const int* __restrict__ imap,
                           const float* __restrict__ sums, const float* __restrict__ cnts){
  const int P = 512*512;
  int b = blockIdx.y;
  __shared__ float lm[96];
  if (threadIdx.x < 96){
    int id = threadIdx.x/3;
    lm[threadIdx.x] = sums[b*96+threadIdx.x] / fmaxf(cnts[b*32+id], 1.0f);
  }
  __syncthreads();
  const int* mb = imap + b*P;
  float* ob = out + b*3*P;
  for (int p = blockIdx.x*blockDim.x + threadIdx.x; p < P; p += gridDim.x*blockDim.x){
    int id = mb[p];
    ob[p]     = lm[id*3+0];
    ob[P+p]   = lm[id*3+1];
    ob[2*P+p] = lm[id*3+2];
  }
}

static inline int cdiv(int a, int b){ return (a+b-1)/b; }

extern "C" void kernel_launch(void* const* d_in, const int* in_sizes, int n_in,
                              void* d_out, int out_size, void* d_ws, size_t ws_size,
                              hipStream_t stream) {
  const float* x    = (const float*)d_in[0];
  const int*   imap = (const int*)d_in[1];
  const float* w_in = (const float*)d_in[2];
  const float* b_in = (const float*)d_in[3];
  const float *wd[4], *bd[4], *wu[4], *bu[4];
  for (int i=0;i<4;i++){ wd[i]=(const float*)d_in[4+2*i];  bd[i]=(const float*)d_in[5+2*i]; }
  for (int i=0;i<4;i++){ wu[i]=(const float*)d_in[12+2*i]; bu[i]=(const float*)d_in[13+2*i]; }
  const float* w_out = (const float*)d_in[20];
  const float* b_out = (const float*)d_in[21];
  float* out = (float*)d_out;

  // workspace layout: A (33.5M f) | B (16.8M f) | mean | invstd | sums | cnts
  char* ws = (char*)d_ws;
  float* A    = (float*)ws;
  float* Bb   = (float*)(ws + (size_t)134217728);
  float* mean = (float*)(ws + (size_t)134217728 + (size_t)67108864);
  float* ivar = mean + 2048;
  float* sums = ivar + 2048;   // [8][32][3]
  float* cnts = sums + 768;    // [8][32]

  auto norm = [&](float* p, int C, int HW, int log2HW){
    in_stats<<<BATCH*C, 256, 0, stream>>>(p, mean, ivar, HW);
    int total4 = BATCH*C*HW/4;
    norm_relu4<<<cdiv(total4,256), 256, 0, stream>>>((float4*)p, mean, ivar, log2HW, total4);
  };

  // conv_in: 3 -> 16 @ 512x512, reflect pad 3
  { int total = BATCH*16*512*512;
    conv7_reflect<3,false><<<cdiv(total,256),256,0,stream>>>(x, w_in, b_in, A, 16, 512, 512, total);
    norm(A, 16, 262144, 18); }

  // down path
  { int total = BATCH*32*256*256;
    conv3s2<16><<<cdiv(total,256),256,0,stream>>>(A, wd[0], bd[0], Bb, 32, 512, 512, total);
    norm(Bb, 32, 65536, 16); }
  { int total = BATCH*64*128*128;
    conv3s2<32><<<cdiv(total,256),256,0,stream>>>(Bb, wd[1], bd[1], A, 64, 256, 256, total);
    norm(A, 64, 16384, 14); }
  { int total = BATCH*128*64*64;
    conv3s2<64><<<cdiv(total,256),256,0,stream>>>(A, wd[2], bd[2], Bb, 128, 128, 128, total);
    norm(Bb, 128, 4096, 12); }
  { int total = BATCH*256*32*32;
    conv3s2<128><<<cdiv(total,256),256,0,stream>>>(Bb, wd[3], bd[3], A, 256, 64, 64, total);
    norm(A, 256, 1024, 10); }

  // up path
  { int total = BATCH*128*64*64;
    tconv3<256><<<cdiv(total,256),256,0,stream>>>(A, wu[0], bu[0], Bb, 128, 32, 32, total);
    norm(Bb, 128, 4096, 12); }
  { int total = BATCH*64*128*128;
    tconv3<128><<<cdiv(total,256),256,0,stream>>>(Bb, wu[1], bu[1], A, 64, 64, 64, total);
    norm(A, 64, 16384, 14); }
  { int total = BATCH*32*256*256;
    tconv3<64><<<cdiv(total,256),256,0,stream>>>(A, wu[2], bu[2], Bb, 32, 128, 128, total);
    norm(Bb, 32, 65536, 16); }
  { int total = BATCH*16*512*512;
    tconv3<32><<<cdiv(total,256),256,0,stream>>>(Bb, wu[3], bu[3], A, 16, 256, 256, total);
    norm(A, 16, 262144, 18); }

  // conv_out: 16 -> 3 @ 512x512, reflect pad 3, tanh
  { int total = BATCH*3*512*512;
    conv7_reflect<16,true><<<cdiv(total,256),256,0,stream>>>(A, w_out, b_out, out, 3, 512, 512, total); }

  // scatter-mean pooling over instance ids
  hipMemsetAsync(sums, 0, (768+256)*sizeof(float), stream);
  pool_accum<<<dim3(64,BATCH),256,0,stream>>>(out, imap, sums, cnts);
  pool_bcast<<<dim3(128,BATCH),256,0,stream>>>(out, imap, sums, cnts);
}

// Round 2
// 3357.890 us; speedup vs baseline: 4.8702x; 4.8702x over previous
//
#include <hip/hip_runtime.h>
#include <math.h>

#define BATCH 8

__device__ __forceinline__ int refl(int p, int n){ return p<0 ? -p : (p>=n ? 2*n-2-p : p); }

// ---------------- conv_in: 3->16, 7x7, reflect pad 3, 512x512, COT=16, PX=4 ----------------
__global__ __launch_bounds__(256) void conv7_in_t(const float* __restrict__ in,
    const float* __restrict__ w, const float* __restrict__ bias, float* __restrict__ out){
  const int H=512, W=512;
  __shared__ float wsm[3*49*16];
  __shared__ float bsm[16];
  for (int t=threadIdx.x; t<2352; t+=256){
    int j = t & 15; int r = t >> 4;           // r = ci*49+kidx
    wsm[t] = w[j*147 + r];
  }
  if (threadIdx.x < 16) bsm[threadIdx.x] = bias[threadIdx.x];
  __syncthreads();
  int idx = blockIdx.x*256 + threadIdx.x;
  int xq = idx & 127; int y = (idx >> 7) & 511; int b = idx >> 16;
  int x0 = xq*4;
  int ry[7], rx[10];
  #pragma unroll
  for (int k=0;k<7;k++) ry[k]=refl(y+k-3,H);
  #pragma unroll
  for (int q=0;q<10;q++) rx[q]=refl(x0+q-3,W);
  float acc[16][4];
  #pragma unroll
  for (int j=0;j<16;j++){ float bv=bsm[j];
    #pragma unroll
    for (int p=0;p<4;p++) acc[j][p]=bv; }
  const float* inb = in + (size_t)b*3*H*W;
  for (int ci=0; ci<3; ++ci){
    const float* ipc = inb + ci*H*W;
    #pragma unroll
    for (int ky=0; ky<7; ++ky){
      const float* row = ipc + ry[ky]*W;
      float rv[10];
      #pragma unroll
      for (int q=0;q<10;q++) rv[q] = row[rx[q]];
      #pragma unroll
      for (int kx=0; kx<7; ++kx){
        const float4* wp = (const float4*)&wsm[(ci*49+ky*7+kx)*16];
        float4 w0=wp[0], w1=wp[1], w2=wp[2], w3=wp[3];
        float wv[16] = {w0.x,w0.y,w0.z,w0.w, w1.x,w1.y,w1.z,w1.w,
                        w2.x,w2.y,w2.z,w2.w, w3.x,w3.y,w3.z,w3.w};
        #pragma unroll
        for (int p=0;p<4;p++){
          float iv = rv[kx+p];
          #pragma unroll
          for (int j=0;j<16;j++) acc[j][p] = fmaf(iv, wv[j], acc[j][p]);
        }
      }
    }
  }
  float* ob = out + ((size_t)(b*16)*H + y)*W + x0;
  #pragma unroll
  for (int j=0;j<16;j++){
    float4 v = {acc[j][0],acc[j][1],acc[j][2],acc[j][3]};
    *(float4*)(ob + (size_t)j*H*W) = v;
  }
}

// ---------------- conv_out: 16->3, 7x7 reflect, tanh, PX=8 ----------------
__global__ __launch_bounds__(256) void conv7_out_t(const float* __restrict__ in,
    const float* __restrict__ w, const float* __restrict__ bias, float* __restrict__ out){
  const int H=512, W=512;
  __shared__ float wsm[16*49*3];
  __shared__ float bsm[3];
  for (int t=threadIdx.x; t<2352; t+=256){
    int j = t % 3; int r = t / 3;             // r = ci*49+kidx
    wsm[t] = w[j*784 + r];
  }
  if (threadIdx.x < 3) bsm[threadIdx.x] = bias[threadIdx.x];
  __syncthreads();
  int idx = blockIdx.x*256 + threadIdx.x;
  int xq = idx & 63; int y = (idx >> 6) & 511; int b = idx >> 15;
  int x0 = xq*8;
  int ry[7], rx[14];
  #pragma unroll
  for (int k=0;k<7;k++) ry[k]=refl(y+k-3,H);
  #pragma unroll
  for (int q=0;q<14;q++) rx[q]=refl(x0+q-3,W);
  float acc[3][8];
  #pragma unroll
  for (int j=0;j<3;j++){ float bv=bsm[j];
    #pragma unroll
    for (int p=0;p<8;p++) acc[j][p]=bv; }
  const float* inb = in + (size_t)b*16*H*W;
  for (int ci=0; ci<16; ++ci){
    const float* ipc = inb + (size_t)ci*H*W;
    #pragma unroll
    for (int ky=0; ky<7; ++ky){
      const float* row = ipc + ry[ky]*W;
      float rv[14];
      #pragma unroll
      for (int q=0;q<14;q++) rv[q] = row[rx[q]];
      #pragma unroll
      for (int kx=0; kx<7; ++kx){
        const float* wp = &wsm[(ci*49+ky*7+kx)*3];
        float w0=wp[0], w1=wp[1], w2=wp[2];
        #pragma unroll
        for (int p=0;p<8;p++){
          float iv = rv[kx+p];
          acc[0][p] = fmaf(iv, w0, acc[0][p]);
          acc[1][p] = fmaf(iv, w1, acc[1][p]);
          acc[2][p] = fmaf(iv, w2, acc[2][p]);
        }
      }
    }
  }
  float* ob = out + ((size_t)(b*3)*H + y)*W + x0;
  #pragma unroll
  for (int j=0;j<3;j++){
    float4 v0 = {tanhf(acc[j][0]),tanhf(acc[j][1]),tanhf(acc[j][2]),tanhf(acc[j][3])};
    float4 v1 = {tanhf(acc[j][4]),tanhf(acc[j][5]),tanhf(acc[j][6]),tanhf(acc[j][7])};
    *(float4*)(ob + (size_t)j*H*W)     = v0;
    *(float4*)(ob + (size_t)j*H*W + 4) = v1;
  }
}

// ---------------- 3x3 stride-2 conv, pad 1; COT=8, PX px per thread ----------------
template<int CIN, int PX>
__global__ __launch_bounds__(256) void conv3s2_t(const float* __restrict__ in,
    const float* __restrict__ w, const float* __restrict__ bias, float* __restrict__ out,
    int Hin, int Win){
  const int Cout = 2*CIN;
  __shared__ float wsm[CIN*8*12];
  int Hout = Hin>>1, Wout = Win>>1, WQ = Wout/PX;
  int idx = blockIdx.x*256 + threadIdx.x;
  int xq = idx % WQ; int t = idx / WQ;
  int y  = t % Hout;  t /= Hout;
  int cot = t % (Cout/8); int b = t / (Cout/8);
  int co0 = cot*8;
  for (int t2=threadIdx.x; t2<CIN*72; t2+=256){
    int k = t2 % 9; int j = (t2/9) % 8; int ci = t2/72;
    wsm[(ci*8+j)*12+k] = w[((size_t)(co0+j)*CIN + ci)*9 + k];
  }
  __syncthreads();
  int x0 = xq*PX; int ix0 = 2*x0-1; int iy0 = 2*y-1;
  float acc[8][PX];
  #pragma unroll
  for (int j=0;j<8;j++){ float bv = bias[co0+j];
    #pragma unroll
    for (int p=0;p<PX;p++) acc[j][p]=bv; }
  const float* inb = in + (size_t)b*CIN*Hin*Win;
  for (int ci=0; ci<CIN; ++ci){
    float rv[3][2*PX+1];
    const float* ip = inb + (size_t)ci*Hin*Win;
    #pragma unroll
    for (int ky=0;ky<3;ky++){
      int iy = iy0+ky;
      bool okY = (unsigned)iy < (unsigned)Hin;
      const float* row = ip + iy*Win;
      #pragma unroll
      for (int q=0;q<2*PX+1;q++){
        int ix = ix0+q;
        rv[ky][q] = (okY && (unsigned)ix<(unsigned)Win) ? row[ix] : 0.f;
      }
    }
    #pragma unroll
    for (int j=0;j<8;j++){
      const float4* wp = (const float4*)&wsm[(ci*8+j)*12];
      float4 a=wp[0], bq=wp[1], c=wp[2];
      float wk[9] = {a.x,a.y,a.z,a.w, bq.x,bq.y,bq.z,bq.w, c.x};
      #pragma unroll
      for (int p=0;p<PX;p++)
        #pragma unroll
        for (int ky=0;ky<3;ky++)
          #pragma unroll
          for (int kx=0;kx<3;kx++)
            acc[j][p] = fmaf(rv[ky][2*p+kx], wk[ky*3+kx], acc[j][p]);
    }
  }
  float* ob = out + (((size_t)b*Cout + co0)*Hout + y)*Wout + x0;
  #pragma unroll
  for (int j=0;j<8;j++){
    if constexpr (PX==4){
      float4 v = {acc[j][0],acc[j][1],acc[j][2],acc[j][3]};
      *(float4*)(ob + (size_t)j*Hout*Wout) = v;
    } else {
      float2 v = {acc[j][0],acc[j][1]};
      *(float2*)(ob + (size_t)j*Hout*Wout) = v;
    }
  }
}

// ---------------- tconv k=3 s=2 p=1 op=1; quad decomposition, PX=2 quads ----------------
template<int CIN, int COT>
__global__ __launch_bounds__(256) void tconv3_t(const float* __restrict__ in,
    const float* __restrict__ w, const float* __restrict__ bias, float* __restrict__ out,
    int Hin, int Win){
  const int PX=2, Cout = CIN/2;
  __shared__ float wsm[CIN*COT*12];
  int Hout = Hin*2, Wout = Win*2, WQ = Win/PX;
  int idx = blockIdx.x*256 + threadIdx.x;
  int xq = idx % WQ; int t = idx / WQ;
  int yo = t % Hin;  t /= Hin;
  int cot = t % (Cout/COT); int b = t / (Cout/COT);
  int co0 = cot*COT;
  for (int t2=threadIdx.x; t2<CIN*COT*9; t2+=256){
    int k = t2 % 9; int j = (t2/9) % COT; int ci = t2/(9*COT);
    wsm[(ci*COT+j)*12+k] = w[((size_t)ci*Cout + co0+j)*9 + k];
  }
  __syncthreads();
  int xo0 = xq*PX;
  float acc[COT][2][2*PX];
  #pragma unroll
  for (int j=0;j<COT;j++){ float bv = bias[co0+j];
    #pragma unroll
    for (int oy=0;oy<2;oy++)
      #pragma unroll
      for (int ox=0;ox<2*PX;ox++) acc[j][oy][ox]=bv; }
  const float* inb = in + (size_t)b*CIN*Hin*Win;
  bool okY1 = (yo+1) < Hin;
  for (int ci=0; ci<CIN; ++ci){
    const float* ip = inb + (size_t)ci*Hin*Win + (size_t)yo*Win;
    float v[2][PX+1];
    #pragma unroll
    for (int c=0;c<PX+1;c++){
      int xc = xo0+c; bool okX = xc < Win;
      v[0][c] = okX ? ip[xc] : 0.f;
      v[1][c] = (okX && okY1) ? ip[Win+xc] : 0.f;
    }
    #pragma unroll
    for (int j=0;j<COT;j++){
      const float4* wp = (const float4*)&wsm[(ci*COT+j)*12];
      float4 a=wp[0], bq=wp[1], c4=wp[2];
      float wk[9] = {a.x,a.y,a.z,a.w, bq.x,bq.y,bq.z,bq.w, c4.x};
      #pragma unroll
      for (int q=0;q<PX;q++){
        float v00=v[0][q], v01=v[0][q+1], v10=v[1][q], v11=v[1][q+1];
        acc[j][0][2*q]   = fmaf(v00, wk[4], acc[j][0][2*q]);
        acc[j][0][2*q+1] = fmaf(v00, wk[5], fmaf(v01, wk[3], acc[j][0][2*q+1]));
        acc[j][1][2*q]   = fmaf(v00, wk[7], fmaf(v10, wk[1], acc[j][1][2*q]));
        acc[j][1][2*q+1] = fmaf(v00, wk[8], fmaf(v01, wk[6],
                           fmaf(v10, wk[2], fmaf(v11, wk[0], acc[j][1][2*q+1]))));
      }
    }
  }
  float* ob = out + (((size_t)b*Cout + co0)*Hout + 2*yo)*Wout + 2*xo0;
  #pragma unroll
  for (int j=0;j<COT;j++){
    float4 r0 = {acc[j][0][0],acc[j][0][1],acc[j][0][2],acc[j][0][3]};
    float4 r1 = {acc[j][1][0],acc[j][1][1],acc[j][1][2],acc[j][1][3]};
    *(float4*)(ob + (size_t)j*Hout*Wout)        = r0;
    *(float4*)(ob + (size_t)j*Hout*Wout + Wout) = r1;
  }
}

// ---------------- instance-norm stats: one block per (b,c) ----------------
__global__ void in_stats(const float* __restrict__ x, float* __restrict__ mean,
                         float* __restrict__ invstd, int HW){
  int bc = blockIdx.x;
  const float* p = x + (size_t)bc*HW;
  float s=0.f, s2=0.f;
  for (int i=threadIdx.x; i<HW; i+=blockDim.x){ float v=p[i]; s+=v; s2=fmaf(v,v,s2); }
  #pragma unroll
  for (int o=32;o>0;o>>=1){ s += __shfl_down(s,o); s2 += __shfl_down(s2,o); }
  __shared__ float sh[8];
  int lane = threadIdx.x & 63, wid = threadIdx.x >> 6;
  if (lane==0){ sh[wid]=s; sh[4+wid]=s2; }
  __syncthreads();
  if (threadIdx.x==0){
    float S  = sh[0]+sh[1]+sh[2]+sh[3];
    float S2 = sh[4]+sh[5]+sh[6]+sh[7];
    float m = S/HW;
    float v = S2/HW - m*m; v = fmaxf(v, 0.f);
    mean[bc]   = m;
    invstd[bc] = rsqrtf(v + 1e-5f);
  }
}

// ---------------- normalize + ReLU in place (float4) ----------------
__global__ void norm_relu4(float4* __restrict__ x, const float* __restrict__ mean,
                           const float* __restrict__ invstd, int log2HW, int total4){
  int idx = blockIdx.x*blockDim.x + threadIdx.x;
  if (idx >= total4) return;
  int bc = (idx<<2) >> log2HW;
  float m = mean[bc], is = invstd[bc];
  float4 v = x[idx];
  v.x = fmaxf((v.x-m)*is, 0.f);
  v.y = fmaxf((v.y-m)*is, 0.f);
  v.z = fmaxf((v.z-m)*is, 0.f);
  v.w = fmaxf((v.w-m)*is, 0.f);
  x[idx] = v;
}

// ---------------- per-(b,id) scatter-mean: accumulate ----------------
__global__ void pool_accum(const float* __restrict__ t, const int* __restrict__ imap,
                           float* __restrict__ sums, float* __restrict__ cnts){
  const int P = 512*512;
  int b = blockIdx.y;
  __shared__ float ls[96];
  __shared__ float lc[32];
  for (int i=threadIdx.x;i<96;i+=blockDim.x) ls[i]=0.f;
  if (threadIdx.x<32) lc[threadIdx.x]=0.f;
  __syncthreads();
  const float* tb = t + (size_t)b*3*P;
  const int*   mb = imap + (size_t)b*P;
  for (int p = blockIdx.x*blockDim.x + threadIdx.x; p < P; p += gridDim.x*blockDim.x){
    int id = mb[p];
    atomicAdd(&ls[id*3+0], tb[p]);
    atomicAdd(&ls[id*3+1], tb[P+p]);
    atomicAdd(&ls[id*3+2], tb[2*P+p]);
    atomicAdd(&lc[id], 1.0f);
  }
  __syncthreads();
  for (int i=threadIdx.x;i<96;i+=blockDim.x) atomicAdd(&sums[b*96+i], ls[i]);
  if (threadIdx.x<32) atomicAdd(&cnts[b*32+threadIdx.x], lc[threadIdx.x]);
}

// ---------------- broadcast means back ----------------
__global__ void pool_bcast(float* __restrict__ out, const int* __restrict__ imap,
                           const float* __restrict__ sums, const float* __restrict__ cnts){
  const int P = 512*512;
  int b = blockIdx.y;
  __shared__ float lm[96];
  if (threadIdx.x < 96){
    int id = threadIdx.x/3;
    lm[threadIdx.x] = sums[b*96+threadIdx.x] / fmaxf(cnts[b*32+id], 1.0f);
  }
  __syncthreads();
  const int* mb = imap + (size_t)b*P;
  float* ob = out + (size_t)b*3*P;
  for (int p = blockIdx.x*blockDim.x + threadIdx.x; p < P; p += gridDim.x*blockDim.x){
    int id = mb[p];
    ob[p]     = lm[id*3+0];
    ob[P+p]   = lm[id*3+1];
    ob[2*P+p] = lm[id*3+2];
  }
}

static inline int cdiv(int a, int b){ return (a+b-1)/b; }

extern "C" void kernel_launch(void* const* d_in, const int* in_sizes, int n_in,
                              void* d_out, int out_size, void* d_ws, size_t ws_size,
                              hipStream_t stream) {
  const float* x    = (const float*)d_in[0];
  const int*   imap = (const int*)d_in[1];
  const float* w_in = (const float*)d_in[2];
  const float* b_in = (const float*)d_in[3];
  const float *wd[4], *bd[4], *wu[4], *bu[4];
  for (int i=0;i<4;i++){ wd[i]=(const float*)d_in[4+2*i];  bd[i]=(const float*)d_in[5+2*i]; }
  for (int i=0;i<4;i++){ wu[i]=(const float*)d_in[12+2*i]; bu[i]=(const float*)d_in[13+2*i]; }
  const float* w_out = (const float*)d_in[20];
  const float* b_out = (const float*)d_in[21];
  float* out = (float*)d_out;

  char* ws = (char*)d_ws;
  float* A    = (float*)ws;
  float* Bb   = (float*)(ws + (size_t)134217728);
  float* mean = (float*)(ws + (size_t)134217728 + (size_t)67108864);
  float* ivar = mean + 2048;
  float* sums = ivar + 2048;   // [8][32][3]
  float* cnts = sums + 768;    // [8][32]

  auto norm = [&](float* p, int C, int HW, int log2HW){
    in_stats<<<BATCH*C, 256, 0, stream>>>(p, mean, ivar, HW);
    int total4 = BATCH*C*HW/4;
    norm_relu4<<<cdiv(total4,256), 256, 0, stream>>>((float4*)p, mean, ivar, log2HW, total4);
  };

  // conv_in: 3 -> 16 @ 512x512
  conv7_in_t<<<2048, 256, 0, stream>>>(x, w_in, b_in, A);
  norm(A, 16, 262144, 18);

  // down path
  conv3s2_t<16,4><<<2048, 256, 0, stream>>>(A,  wd[0], bd[0], Bb, 512, 512);
  norm(Bb, 32, 65536, 16);
  conv3s2_t<32,4><<<1024, 256, 0, stream>>>(Bb, wd[1], bd[1], A,  256, 256);
  norm(A, 64, 16384, 14);
  conv3s2_t<64,4><<< 512, 256, 0, stream>>>(A,  wd[2], bd[2], Bb, 128, 128);
  norm(Bb, 128, 4096, 12);
  conv3s2_t<128,2><<<512, 256, 0, stream>>>(Bb, wd[3], bd[3], A,  64, 64);
  norm(A, 256, 1024, 10);

  // up path
  tconv3_t<256,4><<< 512, 256, 0, stream>>>(A,  wu[0], bu[0], Bb, 32, 32);
  norm(Bb, 128, 4096, 12);
  tconv3_t<128,8><<< 512, 256, 0, stream>>>(Bb, wu[1], bu[1], A,  64, 64);
  norm(A, 64, 16384, 14);
  tconv3_t<64,8><<<1024, 256, 0, stream>>>(A,  wu[2], bu[2], Bb, 128, 128);
  norm(Bb, 32, 65536, 16);
  tconv3_t<32,8><<<2048, 256, 0, stream>>>(Bb, wu[3], bu[3], A,  256, 256);
  norm(A, 16, 262144, 18);

  // conv_out: 16 -> 3 @ 512x512 + tanh
  conv7_out_t<<<1024, 256, 0, stream>>>(A, w_out, b_out, out);

  // scatter-mean pooling over instance ids
  hipMemsetAsync(sums, 0, (768+256)*sizeof(float), stream);
  pool_accum<<<dim3(64,BATCH),256,0,stream>>>(out, imap, sums, cnts);
  pool_bcast<<<dim3(128,BATCH),256,0,stream>>>(out, imap, sums, cnts);
}

// Round 3
// 2861.846 us; speedup vs baseline: 5.7143x; 1.1733x over previous
//
#include <hip/hip_runtime.h>
#include <math.h>

#define BATCH 8
#define EPS 1e-5f

__device__ __forceinline__ int refl(int p, int n){ return p<0 ? -p : (p>=n ? 2*n-2-p : p); }

// stat layout per layer: stat[(b*C + c)*2] = sum, +1 = sumsq (atomic-accumulated)

// ---------------- conv_in: 3->16, 7x7, reflect pad 3, 512x512, COT=16, PX=4 ----------------
__global__ __launch_bounds__(256) void conv7_in_t(const float* __restrict__ in,
    const float* __restrict__ w, const float* __restrict__ bias, float* __restrict__ out,
    float* __restrict__ statOut){
  const int H=512, W=512;
  __shared__ float wsm[3*49*16];
  __shared__ float bsm[16];
  __shared__ float red[4][32];
  for (int t=threadIdx.x; t<2352; t+=256){
    int j = t & 15; int r = t >> 4;
    wsm[t] = w[j*147 + r];
  }
  if (threadIdx.x < 16) bsm[threadIdx.x] = bias[threadIdx.x];
  __syncthreads();
  int idx = blockIdx.x*256 + threadIdx.x;
  int xq = idx & 127; int y = (idx >> 7) & 511; int b = idx >> 16;
  int x0 = xq*4;
  int ry[7], rx[10];
  #pragma unroll
  for (int k=0;k<7;k++) ry[k]=refl(y+k-3,H);
  #pragma unroll
  for (int q=0;q<10;q++) rx[q]=refl(x0+q-3,W);
  float acc[16][4];
  #pragma unroll
  for (int j=0;j<16;j++){ float bv=bsm[j];
    #pragma unroll
    for (int p=0;p<4;p++) acc[j][p]=bv; }
  const float* inb = in + (size_t)b*3*H*W;
  for (int ci=0; ci<3; ++ci){
    const float* ipc = inb + ci*H*W;
    #pragma unroll
    for (int ky=0; ky<7; ++ky){
      const float* row = ipc + ry[ky]*W;
      float rv[10];
      #pragma unroll
      for (int q=0;q<10;q++) rv[q] = row[rx[q]];
      #pragma unroll
      for (int kx=0; kx<7; ++kx){
        const float4* wp = (const float4*)&wsm[(ci*49+ky*7+kx)*16];
        float4 w0=wp[0], w1=wp[1], w2=wp[2], w3=wp[3];
        float wv[16] = {w0.x,w0.y,w0.z,w0.w, w1.x,w1.y,w1.z,w1.w,
                        w2.x,w2.y,w2.z,w2.w, w3.x,w3.y,w3.z,w3.w};
        #pragma unroll
        for (int p=0;p<4;p++){
          float iv = rv[kx+p];
          #pragma unroll
          for (int j=0;j<16;j++) acc[j][p] = fmaf(iv, wv[j], acc[j][p]);
        }
      }
    }
  }
  float* ob = out + ((size_t)(b*16)*H + y)*W + x0;
  #pragma unroll
  for (int j=0;j<16;j++){
    float4 v = {acc[j][0],acc[j][1],acc[j][2],acc[j][3]};
    *(float4*)(ob + (size_t)j*H*W) = v;
  }
  // ---- stats ----
  float ss[16], qq[16];
  #pragma unroll
  for (int j=0;j<16;j++){
    float a=0.f,c=0.f;
    #pragma unroll
    for (int p=0;p<4;p++){ a+=acc[j][p]; c=fmaf(acc[j][p],acc[j][p],c); }
    ss[j]=a; qq[j]=c;
  }
  #pragma unroll
  for (int o=32;o>0;o>>=1){
    #pragma unroll
    for (int j=0;j<16;j++){ ss[j]+=__shfl_down(ss[j],o); qq[j]+=__shfl_down(qq[j],o); }
  }
  int lane = threadIdx.x & 63, wid = threadIdx.x >> 6;
  if (lane==0){
    #pragma unroll
    for (int j=0;j<16;j++){ red[wid][j]=ss[j]; red[wid][16+j]=qq[j]; }
  }
  __syncthreads();
  if (threadIdx.x < 16){
    int j = threadIdx.x;
    float a = red[0][j]+red[1][j]+red[2][j]+red[3][j];
    float c = red[0][16+j]+red[1][16+j]+red[2][16+j]+red[3][16+j];
    float* sp = &statOut[((size_t)b*16 + j)*2];
    atomicAdd(sp, a); atomicAdd(sp+1, c);
  }
}

// ---------------- conv_out: 16->3, 7x7 reflect, tanh, PX=8; normalizes input ----------------
__global__ __launch_bounds__(256) void conv7_out_t(const float* __restrict__ in,
    const float* __restrict__ w, const float* __restrict__ bias, float* __restrict__ out,
    const float* __restrict__ statIn){
  const int H=512, W=512;
  __shared__ float wsm[16*49*3];
  __shared__ float bsm[3];
  __shared__ float msm[16], ism[16];
  for (int t=threadIdx.x; t<2352; t+=256){
    int j = t % 3; int r = t / 3;
    wsm[t] = w[j*784 + r];
  }
  if (threadIdx.x < 3) bsm[threadIdx.x] = bias[threadIdx.x];
  int idx = blockIdx.x*256 + threadIdx.x;
  int xq = idx & 63; int y = (idx >> 6) & 511; int b = idx >> 15;
  if (threadIdx.x < 16){
    const float invHW = 1.f/(512.f*512.f);
    float s  = statIn[((size_t)b*16 + threadIdx.x)*2];
    float s2 = statIn[((size_t)b*16 + threadIdx.x)*2+1];
    float m = s*invHW;
    float v = fmaxf(s2*invHW - m*m, 0.f);
    msm[threadIdx.x] = m; ism[threadIdx.x] = rsqrtf(v + EPS);
  }
  __syncthreads();
  int x0 = xq*8;
  int ry[7], rx[14];
  #pragma unroll
  for (int k=0;k<7;k++) ry[k]=refl(y+k-3,H);
  #pragma unroll
  for (int q=0;q<14;q++) rx[q]=refl(x0+q-3,W);
  float acc[3][8];
  #pragma unroll
  for (int j=0;j<3;j++){ float bv=bsm[j];
    #pragma unroll
    for (int p=0;p<8;p++) acc[j][p]=bv; }
  const float* inb = in + (size_t)b*16*H*W;
  for (int ci=0; ci<16; ++ci){
    const float* ipc = inb + (size_t)ci*H*W;
    float m = msm[ci], is = ism[ci];
    #pragma unroll
    for (int ky=0; ky<7; ++ky){
      const float* row = ipc + ry[ky]*W;
      float rv[14];
      #pragma unroll
      for (int q=0;q<14;q++) rv[q] = fmaxf((row[rx[q]]-m)*is, 0.f);
      #pragma unroll
      for (int kx=0; kx<7; ++kx){
        const float* wp = &wsm[(ci*49+ky*7+kx)*3];
        float w0=wp[0], w1=wp[1], w2=wp[2];
        #pragma unroll
        for (int p=0;p<8;p++){
          float iv = rv[kx+p];
          acc[0][p] = fmaf(iv, w0, acc[0][p]);
          acc[1][p] = fmaf(iv, w1, acc[1][p]);
          acc[2][p] = fmaf(iv, w2, acc[2][p]);
        }
      }
    }
  }
  float* ob = out + ((size_t)(b*3)*H + y)*W + x0;
  #pragma unroll
  for (int j=0;j<3;j++){
    float4 v0 = {tanhf(acc[j][0]),tanhf(acc[j][1]),tanhf(acc[j][2]),tanhf(acc[j][3])};
    float4 v1 = {tanhf(acc[j][4]),tanhf(acc[j][5]),tanhf(acc[j][6]),tanhf(acc[j][7])};
    *(float4*)(ob + (size_t)j*H*W)     = v0;
    *(float4*)(ob + (size_t)j*H*W + 4) = v1;
  }
}

// ---------------- 3x3 stride-2 conv, pad 1; COT=8; normalizes input, emits stats ----------------
template<int CIN, int PX>
__global__ __launch_bounds__(256) void conv3s2_t(const float* __restrict__ in,
    const float* __restrict__ w, const float* __restrict__ bias, float* __restrict__ out,
    int Hin, int Win, const float* __restrict__ statIn, float* __restrict__ statOut){
  const int Cout = 2*CIN;
  __shared__ float wsm[CIN*8*12];
  __shared__ float msm[CIN], ism[CIN];
  __shared__ float red[4][16];
  int Hout = Hin>>1, Wout = Win>>1, WQ = Wout/PX;
  int idx = blockIdx.x*256 + threadIdx.x;
  int xq = idx % WQ; int t = idx / WQ;
  int y  = t % Hout;  t /= Hout;
  int cot = t % (Cout/8); int b = t / (Cout/8);
  int co0 = cot*8;
  for (int t2=threadIdx.x; t2<CIN*72; t2+=256){
    int k = t2 % 9; int j = (t2/9) % 8; int ci = t2/72;
    wsm[(ci*8+j)*12+k] = w[((size_t)(co0+j)*CIN + ci)*9 + k];
  }
  {
    float invHW = 1.f/(float)(Hin*Win);
    for (int t2=threadIdx.x; t2<CIN; t2+=256){
      float s  = statIn[((size_t)b*CIN + t2)*2];
      float s2 = statIn[((size_t)b*CIN + t2)*2+1];
      float m = s*invHW;
      float v = fmaxf(s2*invHW - m*m, 0.f);
      msm[t2] = m; ism[t2] = rsqrtf(v + EPS);
    }
  }
  __syncthreads();
  int x0 = xq*PX; int ix0 = 2*x0-1; int iy0 = 2*y-1;
  float acc[8][PX];
  #pragma unroll
  for (int j=0;j<8;j++){ float bv = bias[co0+j];
    #pragma unroll
    for (int p=0;p<PX;p++) acc[j][p]=bv; }
  const float* inb = in + (size_t)b*CIN*Hin*Win;
  for (int ci=0; ci<CIN; ++ci){
    float rv[3][2*PX+1];
    const float* ip = inb + (size_t)ci*Hin*Win;
    float m = msm[ci], is = ism[ci];
    #pragma unroll
    for (int ky=0;ky<3;ky++){
      int iy = iy0+ky;
      bool okY = (unsigned)iy < (unsigned)Hin;
      const float* row = ip + iy*Win;
      #pragma unroll
      for (int q=0;q<2*PX+1;q++){
        int ix = ix0+q;
        rv[ky][q] = (okY && (unsigned)ix<(unsigned)Win) ? fmaxf((row[ix]-m)*is,0.f) : 0.f;
      }
    }
    #pragma unroll
    for (int j=0;j<8;j++){
      const float4* wp = (const float4*)&wsm[(ci*8+j)*12];
      float4 a=wp[0], bq=wp[1], c=wp[2];
      float wk[9] = {a.x,a.y,a.z,a.w, bq.x,bq.y,bq.z,bq.w, c.x};
      #pragma unroll
      for (int p=0;p<PX;p++)
        #pragma unroll
        for (int ky=0;ky<3;ky++)
          #pragma unroll
          for (int kx=0;kx<3;kx++)
            acc[j][p] = fmaf(rv[ky][2*p+kx], wk[ky*3+kx], acc[j][p]);
    }
  }
  float* ob = out + (((size_t)b*Cout + co0)*Hout + y)*Wout + x0;
  #pragma unroll
  for (int j=0;j<8;j++){
    if constexpr (PX==4){
      float4 v = {acc[j][0],acc[j][1],acc[j][2],acc[j][3]};
      *(float4*)(ob + (size_t)j*Hout*Wout) = v;
    } else {
      float2 v = {acc[j][0],acc[j][1]};
      *(float2*)(ob + (size_t)j*Hout*Wout) = v;
    }
  }
  // ---- stats ----
  float ss[8], qq[8];
  #pragma unroll
  for (int j=0;j<8;j++){
    float a=0.f,c=0.f;
    #pragma unroll
    for (int p=0;p<PX;p++){ a+=acc[j][p]; c=fmaf(acc[j][p],acc[j][p],c); }
    ss[j]=a; qq[j]=c;
  }
  #pragma unroll
  for (int o=32;o>0;o>>=1){
    #pragma unroll
    for (int j=0;j<8;j++){ ss[j]+=__shfl_down(ss[j],o); qq[j]+=__shfl_down(qq[j],o); }
  }
  int lane = threadIdx.x & 63, wid = threadIdx.x >> 6;
  if (lane==0){
    #pragma unroll
    for (int j=0;j<8;j++){ red[wid][j]=ss[j]; red[wid][8+j]=qq[j]; }
  }
  __syncthreads();
  if (threadIdx.x < 8){
    int j = threadIdx.x;
    float a = red[0][j]+red[1][j]+red[2][j]+red[3][j];
    float c = red[0][8+j]+red[1][8+j]+red[2][8+j]+red[3][8+j];
    float* sp = &statOut[((size_t)b*Cout + co0 + j)*2];
    atomicAdd(sp, a); atomicAdd(sp+1, c);
  }
}

// ---------------- tconv k=3 s=2 p=1 op=1; normalizes input, emits stats ----------------
template<int CIN, int COT>
__global__ __launch_bounds__(256) void tconv3_t(const float* __restrict__ in,
    const float* __restrict__ w, const float* __restrict__ bias, float* __restrict__ out,
    int Hin, int Win, const float* __restrict__ statIn, float* __restrict__ statOut){
  const int PX=2, Cout = CIN/2;
  __shared__ float wsm[CIN*COT*12];
  __shared__ float msm[CIN], ism[CIN];
  __shared__ float red[4][2*COT];
  int Hout = Hin*2, Wout = Win*2, WQ = Win/PX;
  int idx = blockIdx.x*256 + threadIdx.x;
  int xq = idx % WQ; int t = idx / WQ;
  int yo = t % Hin;  t /= Hin;
  int cot = t % (Cout/COT); int b = t / (Cout/COT);
  int co0 = cot*COT;
  for (int t2=threadIdx.x; t2<CIN*COT*9; t2+=256){
    int k = t2 % 9; int j = (t2/9) % COT; int ci = t2/(9*COT);
    wsm[(ci*COT+j)*12+k] = w[((size_t)ci*Cout + co0+j)*9 + k];
  }
  {
    float invHW = 1.f/(float)(Hin*Win);
    for (int t2=threadIdx.x; t2<CIN; t2+=256){
      float s  = statIn[((size_t)b*CIN + t2)*2];
      float s2 = statIn[((size_t)b*CIN + t2)*2+1];
      float m = s*invHW;
      float v = fmaxf(s2*invHW - m*m, 0.f);
      msm[t2] = m; ism[t2] = rsqrtf(v + EPS);
    }
  }
  __syncthreads();
  int xo0 = xq*PX;
  float acc[COT][2][2*PX];
  #pragma unroll
  for (int j=0;j<COT;j++){ float bv = bias[co0+j];
    #pragma unroll
    for (int oy=0;oy<2;oy++)
      #pragma unroll
      for (int ox=0;ox<2*PX;ox++) acc[j][oy][ox]=bv; }
  const float* inb = in + (size_t)b*CIN*Hin*Win;
  bool okY1 = (yo+1) < Hin;
  for (int ci=0; ci<CIN; ++ci){
    const float* ip = inb + (size_t)ci*Hin*Win + (size_t)yo*Win;
    float m = msm[ci], is = ism[ci];
    float v[2][PX+1];
    #pragma unroll
    for (int c=0;c<PX+1;c++){
      int xc = xo0+c; bool okX = xc < Win;
      v[0][c] = okX ? fmaxf((ip[xc]-m)*is,0.f) : 0.f;
      v[1][c] = (okX && okY1) ? fmaxf((ip[Win+xc]-m)*is,0.f) : 0.f;
    }
    #pragma unroll
    for (int j=0;j<COT;j++){
      const float4* wp = (const float4*)&wsm[(ci*COT+j)*12];
      float4 a=wp[0], bq=wp[1], c4=wp[2];
      float wk[9] = {a.x,a.y,a.z,a.w, bq.x,bq.y,bq.z,bq.w, c4.x};
      #pragma unroll
      for (int q=0;q<PX;q++){
        float v00=v[0][q], v01=v[0][q+1], v10=v[1][q], v11=v[1][q+1];
        acc[j][0][2*q]   = fmaf(v00, wk[4], acc[j][0][2*q]);
        acc[j][0][2*q+1] = fmaf(v00, wk[5], fmaf(v01, wk[3], acc[j][0][2*q+1]));
        acc[j][1][2*q]   = fmaf(v00, wk[7], fmaf(v10, wk[1], acc[j][1][2*q]));
        acc[j][1][2*q+1] = fmaf(v00, wk[8], fmaf(v01, wk[6],
                           fmaf(v10, wk[2], fmaf(v11, wk[0], acc[j][1][2*q+1]))));
      }
    }
  }
  float* ob = out + (((size_t)b*Cout + co0)*Hout + 2*yo)*Wout + 2*xo0;
  #pragma unroll
  for (int j=0;j<COT;j++){
    float4 r0 = {acc[j][0][0],acc[j][0][1],acc[j][0][2],acc[j][0][3]};
    float4 r1 = {acc[j][1][0],acc[j][1][1],acc[j][1][2],acc[j][1][3]};
    *(float4*)(ob + (size_t)j*Hout*Wout)        = r0;
    *(float4*)(ob + (size_t)j*Hout*Wout + Wout) = r1;
  }
  // ---- stats ----
  float ss[COT], qq[COT];
  #pragma unroll
  for (int j=0;j<COT;j++){
    float a=0.f,c=0.f;
    #pragma unroll
    for (int oy=0;oy<2;oy++)
      #pragma unroll
      for (int ox=0;ox<2*PX;ox++){ float u=acc[j][oy][ox]; a+=u; c=fmaf(u,u,c); }
    ss[j]=a; qq[j]=c;
  }
  #pragma unroll
  for (int o=32;o>0;o>>=1){
    #pragma unroll
    for (int j=0;j<COT;j++){ ss[j]+=__shfl_down(ss[j],o); qq[j]+=__shfl_down(qq[j],o); }
  }
  int lane = threadIdx.x & 63, wid = threadIdx.x >> 6;
  if (lane==0){
    #pragma unroll
    for (int j=0;j<COT;j++){ red[wid][j]=ss[j]; red[wid][COT+j]=qq[j]; }
  }
  __syncthreads();
  if (threadIdx.x < COT){
    int j = threadIdx.x;
    float a = red[0][j]+red[1][j]+red[2][j]+red[3][j];
    float c = red[0][COT+j]+red[1][COT+j]+red[2][COT+j]+red[3][COT+j];
    float* sp = &statOut[((size_t)b*Cout + co0 + j)*2];
    atomicAdd(sp, a); atomicAdd(sp+1, c);
  }
}

// ---------------- per-(b,id) scatter-mean: accumulate ----------------
__global__ void pool_accum(const float* __restrict__ t, const int* __restrict__ imap,
                           float* __restrict__ sums, float* __restrict__ cnts){
  const int P = 512*512;
  int b = blockIdx.y;
  __shared__ float ls[96];
  __shared__ float lc[32];
  for (int i=threadIdx.x;i<96;i+=blockDim.x) ls[i]=0.f;
  if (threadIdx.x<32) lc[threadIdx.x]=0.f;
  __syncthreads();
  const float* tb = t + (size_t)b*3*P;
  const int*   mb = imap + (size_t)b*P;
  for (int p = blockIdx.x*blockDim.x + threadIdx.x; p < P; p += gridDim.x*blockDim.x){
    int id = mb[p];
    atomicAdd(&ls[id*3+0], tb[p]);
    atomicAdd(&ls[id*3+1], tb[P+p]);
    atomicAdd(&ls[id*3+2], tb[2*P+p]);
    atomicAdd(&lc[id], 1.0f);
  }
  __syncthreads();
  for (int i=threadIdx.x;i<96;i+=blockDim.x) atomicAdd(&sums[b*96+i], ls[i]);
  if (threadIdx.x<32) atomicAdd(&cnts[b*32+threadIdx.x], lc[threadIdx.x]);
}

// ---------------- broadcast means back ----------------
__global__ void pool_bcast(float* __restrict__ out, const int* __restrict__ imap,
                           const float* __restrict__ sums, const float* __restrict__ cnts){
  const int P = 512*512;
  int b = blockIdx.y;
  __shared__ float lm[96];
  if (threadIdx.x < 96){
    int id = threadIdx.x/3;
    lm[threadIdx.x] = sums[b*96+threadIdx.x] / fmaxf(cnts[b*32+id], 1.0f);
  }
  __syncthreads();
  const int* mb = imap + (size_t)b*P;
  float* ob = out + (size_t)b*3*P;
  for (int p = blockIdx.x*blockDim.x + threadIdx.x; p < P; p += gridDim.x*blockDim.x){
    int id = mb[p];
    ob[p]     = lm[id*3+0];
    ob[P+p]   = lm[id*3+1];
    ob[2*P+p] = lm[id*3+2];
  }
}

static inline int cdiv(int a, int b){ return (a+b-1)/b; }

extern "C" void kernel_launch(void* const* d_in, const int* in_sizes, int n_in,
                              void* d_out, int out_size, void* d_ws, size_t ws_size,
                              hipStream_t stream) {
  const float* x    = (const float*)d_in[0];
  const int*   imap = (const int*)d_in[1];
  const float* w_in = (const float*)d_in[2];
  const float* b_in = (const float*)d_in[3];
  const float *wd[4], *bd[4], *wu[4], *bu[4];
  for (int i=0;i<4;i++){ wd[i]=(const float*)d_in[4+2*i];  bd[i]=(const float*)d_in[5+2*i]; }
  for (int i=0;i<4;i++){ wu[i]=(const float*)d_in[12+2*i]; bu[i]=(const float*)d_in[13+2*i]; }
  const float* w_out = (const float*)d_in[20];
  const float* b_out = (const float*)d_in[21];
  float* out = (float*)d_out;

  char* ws = (char*)d_ws;
  float* A     = (float*)ws;
  float* Bb    = (float*)(ws + (size_t)134217728);
  float* stats = (float*)(ws + (size_t)134217728 + (size_t)67108864);
  // per-layer stat bases (floats): [(b*C+c)*2]
  float* stLin = stats;          // 8*16*2  = 256
  float* std0  = stLin + 256;    // 8*32*2  = 512
  float* std1  = std0  + 512;    // 8*64*2  = 1024
  float* std2  = std1  + 1024;   // 8*128*2 = 2048
  float* std3  = std2  + 2048;   // 8*256*2 = 4096
  float* stu0  = std3  + 4096;   // 8*128*2 = 2048
  float* stu1  = stu0  + 2048;   // 8*64*2  = 1024
  float* stu2  = stu1  + 1024;   // 8*32*2  = 512
  float* stu3  = stu2  + 512;    // 8*16*2  = 256
  float* sums  = stu3  + 256;    // [8][32][3] = 768
  float* cnts  = sums  + 768;    // [8][32]    = 256
  // zero all stats + pool accumulators in one shot: (11776 + 1024) floats
  hipMemsetAsync(stats, 0, (size_t)(11776 + 1024)*sizeof(float), stream);

  // conv_in: 3 -> 16 @ 512x512 (raw input, emits stLin)
  conv7_in_t<<<2048, 256, 0, stream>>>(x, w_in, b_in, A, stLin);

  // down path (normalize input via statIn, emit statOut)
  conv3s2_t<16,4><<<2048, 256, 0, stream>>>(A,  wd[0], bd[0], Bb, 512, 512, stLin, std0);
  conv3s2_t<32,4><<<1024, 256, 0, stream>>>(Bb, wd[1], bd[1], A,  256, 256, std0, std1);
  conv3s2_t<64,4><<< 512, 256, 0, stream>>>(A,  wd[2], bd[2], Bb, 128, 128, std1, std2);
  conv3s2_t<128,2><<<512, 256, 0, stream>>>(Bb, wd[3], bd[3], A,   64,  64, std2, std3);

  // up path
  tconv3_t<256,4><<< 512, 256, 0, stream>>>(A,  wu[0], bu[0], Bb, 32, 32, std3, stu0);
  tconv3_t<128,8><<< 512, 256, 0, stream>>>(Bb, wu[1], bu[1], A,  64, 64, stu0, stu1);
  tconv3_t<64,8><<<1024, 256, 0, stream>>>(A,  wu[2], bu[2], Bb, 128, 128, stu1, stu2);
  tconv3_t<32,8><<<2048, 256, 0, stream>>>(Bb, wu[3], bu[3], A,  256, 256, stu2, stu3);

  // conv_out: 16 -> 3 @ 512x512 + tanh (normalizes u3 on load)
  conv7_out_t<<<1024, 256, 0, stream>>>(A, w_out, b_out, out, stu3);

  // scatter-mean pooling over instance ids
  pool_accum<<<dim3(64,BATCH),256,0,stream>>>(out, imap, sums, cnts);
  pool_bcast<<<dim3(128,BATCH),256,0,stream>>>(out, imap, sums, cnts);
}